// Round 1
// baseline (1246.305 us; speedup 1.0000x reference)
//
#include <hip/hip_runtime.h>

#define KK 5
#define KK2 25
#define FIN 64
#define HH 16
#define CC 7

// ---------------- kernel 1: per-edge spline basis + degree ----------------
__global__ void k_prep(const float* __restrict__ attr, const int* __restrict__ ei,
                       float4* __restrict__ basis, unsigned* __restrict__ wiPack,
                       float* __restrict__ deg, int E) {
    int e = blockIdx.x * 256 + threadIdx.x;
    if (e >= E) return;
    float a0 = attr[2 * e], a1 = attr[2 * e + 1];
    float v0 = a0 * 4.0f, v1 = a1 * 4.0f;
    float l0 = floorf(v0), l1 = floorf(v1);
    float f0 = v0 - l0, f1 = v1 - l1;
    int i0 = (int)l0, i1 = (int)l1;
    int i0a = min(max(i0, 0), 4), i0b = min(max(i0 + 1, 0), 4);
    int i1a = min(max(i1, 0), 4), i1b = min(max(i1 + 1, 0), 4);
    float g0a = 1.0f - f0, g0b = f0, g1a = 1.0f - f1, g1b = f1;
    float4 b;
    b.x = g0a * g1a;   // (b0=0,b1=0)
    b.y = g0b * g1a;   // (1,0)
    b.z = g0a * g1b;   // (0,1)
    b.w = g0b * g1b;   // (1,1)
    unsigned w0 = (unsigned)(i0a * 5 + i1a);
    unsigned w1 = (unsigned)(i0b * 5 + i1a);
    unsigned w2 = (unsigned)(i0a * 5 + i1b);
    unsigned w3 = (unsigned)(i0b * 5 + i1b);
    basis[e] = b;
    wiPack[e] = w0 | (w1 << 8) | (w2 << 16) | (w3 << 24);
    int d = ei[E + e];
    atomicAdd(&deg[d], 1.0f);
}

// ---------------- kernel 2a: repack weights ----------------
// B1t[c][i] = W1[k][i][h], c = k*16+h   (400 x 64)
// W2p[k][i][0..7] = W2[k][i][c] padded to 8 (25 x 16 x 8)
__global__ void k_prepW(const float* __restrict__ W1, const float* __restrict__ W2,
                        float* __restrict__ B1t, float* __restrict__ W2p) {
    int tid = blockIdx.x * 256 + threadIdx.x;
    if (tid < KK2 * FIN * HH) {
        int c = tid >> 6, i = tid & 63;
        int k = c >> 4, h = c & 15;
        B1t[tid] = W1[(k * FIN + i) * HH + h];
    }
    if (tid < KK2 * HH * CC) {
        int k = tid / (HH * CC), r = tid % (HH * CC);
        int i = r / CC, c = r % CC;
        W2p[(k * HH + i) * 8 + c] = W2[tid];
    }
}

// ---------------- kernel 2: y1 = x @ W1 (all 25 kernels), [N,400] ----------------
// block-uniform q (column quarter) so B1t loads are scalar(ish); x row in regs.
__global__ void k_y1(const float* __restrict__ x, const float* __restrict__ B1t,
                     float* __restrict__ y1, int N, int nb) {
    int q = blockIdx.x / nb;                  // 0..3, block-uniform
    int n = (blockIdx.x % nb) * 256 + threadIdx.x;
    if (n >= N) return;
    float4 xr[16];
    const float4* xp = (const float4*)(x + (size_t)n * 64);
#pragma unroll
    for (int i = 0; i < 16; i++) xr[i] = xp[i];
    const float* B = B1t + q * 100 * 64;
    float* yo = y1 + (size_t)n * 400 + q * 100;
    for (int c = 0; c < 100; c++) {
        const float4* bp = (const float4*)(B + c * 64);
        float acc = 0.0f;
#pragma unroll
        for (int i = 0; i < 16; i++) {
            float4 b = bp[i];
            acc += xr[i].x * b.x + xr[i].y * b.y + xr[i].z * b.z + xr[i].w * b.w;
        }
        yo[c] = acc;
    }
}

// ---------------- kernel 3: layer-1 edge scatter ----------------
__global__ void k_sc1(const int* __restrict__ ei, const float4* __restrict__ basis,
                      const unsigned* __restrict__ wiPack, const float* __restrict__ y1,
                      float* __restrict__ agg1, int E) {
    int e = blockIdx.x * 256 + threadIdx.x;
    if (e >= E) return;
    int s = ei[e], d = ei[E + e];
    float4 b = basis[e];
    unsigned w = wiPack[e];
    float bt[4] = {b.x, b.y, b.z, b.w};
    int kk[4] = {(int)(w & 255u), (int)((w >> 8) & 255u),
                 (int)((w >> 16) & 255u), (int)(w >> 24)};
    float m[16];
#pragma unroll
    for (int h = 0; h < 16; h++) m[h] = 0.0f;
    const float* yr = y1 + (size_t)s * 400;
#pragma unroll
    for (int t = 0; t < 4; t++) {
        const float4* p = (const float4*)(yr + kk[t] * 16);
        float bb = bt[t];
#pragma unroll
        for (int j = 0; j < 4; j++) {
            float4 v = p[j];
            m[4 * j + 0] += bb * v.x;
            m[4 * j + 1] += bb * v.y;
            m[4 * j + 2] += bb * v.z;
            m[4 * j + 3] += bb * v.w;
        }
    }
    float* ag = agg1 + (size_t)d * 16;
#pragma unroll
    for (int h = 0; h < 16; h++) atomicAdd(ag + h, m[h]);
}

// ---------------- kernel 4: node update 1 (mean + root + bias, relu) ----------------
__global__ void k_upd1(const float* __restrict__ x, const float* __restrict__ agg1,
                       const float* __restrict__ deg, const float* __restrict__ root1,
                       const float* __restrict__ bias1, float* __restrict__ h1, int N) {
    int n = blockIdx.x * 256 + threadIdx.x;
    if (n >= N) return;
    float inv = 1.0f / fmaxf(deg[n], 1.0f);
    float r[16];
#pragma unroll
    for (int h = 0; h < 16; h++) r[h] = agg1[(size_t)n * 16 + h] * inv + bias1[h];
    const float* xrow = x + (size_t)n * 64;
    for (int i = 0; i < 64; i++) {
        float xi = xrow[i];
        const float* rr = root1 + i * 16;
#pragma unroll
        for (int h = 0; h < 16; h++) r[h] += xi * rr[h];
    }
    float* ho = h1 + (size_t)n * 16;
#pragma unroll
    for (int h = 0; h < 16; h++) ho[h] = fmaxf(r[h], 0.0f);
}

// ---------------- kernel 5: layer-2 edge scatter (direct, W2 L1-resident) ----------------
__global__ void k_sc2(const int* __restrict__ ei, const float4* __restrict__ basis,
                      const unsigned* __restrict__ wiPack, const float* __restrict__ h1,
                      const float* __restrict__ W2p, float* __restrict__ agg2, int E) {
    int e = blockIdx.x * 256 + threadIdx.x;
    if (e >= E) return;
    int s = ei[e], d = ei[E + e];
    float4 b = basis[e];
    unsigned w = wiPack[e];
    float bt[4] = {b.x, b.y, b.z, b.w};
    int kk[4] = {(int)(w & 255u), (int)((w >> 8) & 255u),
                 (int)((w >> 16) & 255u), (int)(w >> 24)};
    float hreg[16];
    const float4* hp = (const float4*)(h1 + (size_t)s * 16);
#pragma unroll
    for (int j = 0; j < 4; j++) {
        float4 v = hp[j];
        hreg[4 * j + 0] = v.x; hreg[4 * j + 1] = v.y;
        hreg[4 * j + 2] = v.z; hreg[4 * j + 3] = v.w;
    }
    float a0 = 0, a1 = 0, a2 = 0, a3 = 0, a4 = 0, a5 = 0, a6 = 0;
#pragma unroll
    for (int t = 0; t < 4; t++) {
        const float4* p = (const float4*)(W2p + kk[t] * 128);
        float bb = bt[t];
#pragma unroll
        for (int i = 0; i < 16; i++) {
            float wv = bb * hreg[i];
            float4 lo = p[2 * i], hi = p[2 * i + 1];
            a0 += wv * lo.x; a1 += wv * lo.y; a2 += wv * lo.z; a3 += wv * lo.w;
            a4 += wv * hi.x; a5 += wv * hi.y; a6 += wv * hi.z;
        }
    }
    float* ag = agg2 + (size_t)d * 7;
    atomicAdd(ag + 0, a0); atomicAdd(ag + 1, a1); atomicAdd(ag + 2, a2);
    atomicAdd(ag + 3, a3); atomicAdd(ag + 4, a4); atomicAdd(ag + 5, a5);
    atomicAdd(ag + 6, a6);
}

// ---------------- kernel 6: final node update + log_softmax ----------------
__global__ void k_fin(const float* __restrict__ h1, const float* __restrict__ agg2,
                      const float* __restrict__ deg, const float* __restrict__ root2,
                      const float* __restrict__ bias2, float* __restrict__ out, int N) {
    int n = blockIdx.x * 256 + threadIdx.x;
    if (n >= N) return;
    float inv = 1.0f / fmaxf(deg[n], 1.0f);
    float z[7];
#pragma unroll
    for (int c = 0; c < 7; c++) z[c] = agg2[(size_t)n * 7 + c] * inv + bias2[c];
    const float* hrow = h1 + (size_t)n * 16;
#pragma unroll
    for (int i = 0; i < 16; i++) {
        float hi = hrow[i];
        const float* rr = root2 + i * 7;
#pragma unroll
        for (int c = 0; c < 7; c++) z[c] += hi * rr[c];
    }
    float m = z[0];
#pragma unroll
    for (int c = 1; c < 7; c++) m = fmaxf(m, z[c]);
    float ssum = 0.0f;
#pragma unroll
    for (int c = 0; c < 7; c++) ssum += expf(z[c] - m);
    float ls = logf(ssum);
    float* orow = out + (size_t)n * 7;
#pragma unroll
    for (int c = 0; c < 7; c++) orow[c] = z[c] - m - ls;
}

extern "C" void kernel_launch(void* const* d_in, const int* in_sizes, int n_in,
                              void* d_out, int out_size, void* d_ws, size_t ws_size,
                              hipStream_t stream) {
    const float* x     = (const float*)d_in[0];
    const int*   ei    = (const int*)d_in[1];
    const float* attr  = (const float*)d_in[2];
    const float* W1    = (const float*)d_in[3];
    const float* root1 = (const float*)d_in[4];
    const float* bias1 = (const float*)d_in[5];
    const float* W2    = (const float*)d_in[6];
    const float* root2 = (const float*)d_in[7];
    const float* bias2 = (const float*)d_in[8];
    float* out = (float*)d_out;

    int N = in_sizes[0] / FIN;
    int E = in_sizes[1] / 2;

    char* w = (char*)d_ws;
    size_t off = 0;
    auto alloc = [&](size_t bytes) -> void* {
        void* p = w + off;
        off += (bytes + 255) & ~(size_t)255;
        return p;
    };
    float4*   basis  = (float4*)alloc((size_t)E * 16);
    unsigned* wiPack = (unsigned*)alloc((size_t)E * 4);
    float*    deg    = (float*)alloc((size_t)N * 4);
    float*    agg1   = (float*)alloc((size_t)N * 64);
    float*    h1     = (float*)alloc((size_t)N * 64);
    float*    agg2   = (float*)alloc((size_t)N * 28);
    float*    B1t    = (float*)alloc((size_t)KK2 * FIN * HH * 4);
    float*    W2p    = (float*)alloc((size_t)KK2 * HH * 8 * 4);
    float*    y1     = (float*)alloc((size_t)N * 400 * 4);
    (void)ws_size; (void)n_in; (void)out_size;

    hipMemsetAsync(deg, 0, (size_t)N * 4, stream);
    hipMemsetAsync(agg1, 0, (size_t)N * 64, stream);
    hipMemsetAsync(agg2, 0, (size_t)N * 28, stream);

    int ebl = (E + 255) / 256;
    int nbl = (N + 255) / 256;

    k_prep<<<ebl, 256, 0, stream>>>(attr, ei, basis, wiPack, deg, E);
    k_prepW<<<(KK2 * FIN * HH + 255) / 256, 256, 0, stream>>>(W1, W2, B1t, W2p);
    k_y1<<<4 * nbl, 256, 0, stream>>>(x, B1t, y1, N, nbl);
    k_sc1<<<ebl, 256, 0, stream>>>(ei, basis, wiPack, y1, agg1, E);
    k_upd1<<<nbl, 256, 0, stream>>>(x, agg1, deg, root1, bias1, h1, N);
    k_sc2<<<ebl, 256, 0, stream>>>(ei, basis, wiPack, h1, W2p, agg2, E);
    k_fin<<<nbl, 256, 0, stream>>>(h1, agg2, deg, root2, bias2, out, N);
}

// Round 2
// 598.137 us; speedup vs baseline: 2.0836x; 2.0836x over previous
//
#include <hip/hip_runtime.h>

#define KK2 25
#define FIN 64
#define HH 16
#define CC 7

// ---------------- histogram of dst degrees (int atomics) ----------------
__global__ void k_hist(const int* __restrict__ ei, int* __restrict__ cnt, int E) {
    int e = blockIdx.x * 256 + threadIdx.x;
    if (e < E) atomicAdd(&cnt[ei[E + e]], 1);
}

// ---------------- single-block exclusive scan over N counts ----------------
__global__ __launch_bounds__(1024) void k_scan(const int* __restrict__ cnt,
                                               int* __restrict__ rowStart,
                                               int* __restrict__ cursor, int N) {
    int t = threadIdx.x;
    const int CH = (N + 1023) / 1024;
    int base = t * CH, end = min(base + CH, N);
    int local = 0;
    for (int i = base; i < end; i++) local += cnt[i];
    __shared__ int sd[1024];
    sd[t] = local;
    __syncthreads();
    for (int off = 1; off < 1024; off <<= 1) {
        int v = (t >= off) ? sd[t - off] : 0;
        __syncthreads();
        sd[t] += v;
        __syncthreads();
    }
    int run = (t == 0) ? 0 : sd[t - 1];
    for (int i = base; i < end; i++) {
        rowStart[i] = run; cursor[i] = run; run += cnt[i];
    }
    if (base < N && end == N) rowStart[N] = run;
}

// ---------------- scatter edges into dst-sorted order (basis computed inline) ----------------
__global__ void k_scatter(const float* __restrict__ attr, const int* __restrict__ ei,
                          int* __restrict__ cursor, int* __restrict__ eSrc,
                          float4* __restrict__ eBasis, unsigned* __restrict__ eWi, int E) {
    int e = blockIdx.x * 256 + threadIdx.x;
    if (e >= E) return;
    float v0 = attr[2 * e] * 4.0f, v1 = attr[2 * e + 1] * 4.0f;
    float l0 = floorf(v0), l1 = floorf(v1);
    float f0 = v0 - l0, f1 = v1 - l1;
    int i0 = (int)l0, i1 = (int)l1;
    int i0a = min(max(i0, 0), 4), i0b = min(max(i0 + 1, 0), 4);
    int i1a = min(max(i1, 0), 4), i1b = min(max(i1 + 1, 0), 4);
    float4 b;
    b.x = (1.0f - f0) * (1.0f - f1);
    b.y = f0 * (1.0f - f1);
    b.z = (1.0f - f0) * f1;
    b.w = f0 * f1;
    unsigned pack = (unsigned)(i0a * 5 + i1a) | ((unsigned)(i0b * 5 + i1a) << 8) |
                    ((unsigned)(i0a * 5 + i1b) << 16) | ((unsigned)(i0b * 5 + i1b) << 24);
    int s = ei[e], d = ei[E + e];
    int pos = atomicAdd(&cursor[d], 1);
    eSrc[pos] = s;
    eBasis[pos] = b;
    eWi[pos] = pack;
}

// ---------------- repack weights ----------------
__global__ void k_prepW(const float* __restrict__ W1, const float* __restrict__ W2,
                        float* __restrict__ B1t, float* __restrict__ W2p) {
    int tid = blockIdx.x * 256 + threadIdx.x;
    if (tid < KK2 * FIN * HH) {
        int c = tid >> 6, i = tid & 63;
        int k = c >> 4, h = c & 15;
        B1t[tid] = W1[(k * FIN + i) * HH + h];
    }
    if (tid < KK2 * HH * CC) {
        int k = tid / (HH * CC), r = tid % (HH * CC);
        int i = r / CC, c = r % CC;
        W2p[(k * HH + i) * 8 + c] = W2[tid];
    }
}

// ---------------- y1 = x @ W1 (all 25 kernels), [N,400] ----------------
__global__ void k_y1(const float* __restrict__ x, const float* __restrict__ B1t,
                     float* __restrict__ y1, int N, int nb) {
    int q = blockIdx.x / nb;                  // 0..3, block-uniform
    int n = (blockIdx.x % nb) * 256 + threadIdx.x;
    if (n >= N) return;
    float4 xr[16];
    const float4* xp = (const float4*)(x + (size_t)n * 64);
#pragma unroll
    for (int i = 0; i < 16; i++) xr[i] = xp[i];
    const float* B = B1t + q * 100 * 64;
    float* yo = y1 + (size_t)n * 400 + q * 100;
    for (int c = 0; c < 100; c++) {
        const float4* bp = (const float4*)(B + c * 64);
        float acc = 0.0f;
#pragma unroll
        for (int i = 0; i < 16; i++) {
            float4 b = bp[i];
            acc += xr[i].x * b.x + xr[i].y * b.y + xr[i].z * b.z + xr[i].w * b.w;
        }
        yo[c] = acc;
    }
}

// ---------------- layer-1 aggregation: one wave per node, no atomics ----------------
__global__ void k_agg1(const int* __restrict__ rowStart, const int* __restrict__ eSrc,
                       const float4* __restrict__ eBasis, const unsigned* __restrict__ eWi,
                       const float* __restrict__ y1, float* __restrict__ agg1, int N) {
    int n = blockIdx.x * 4 + (threadIdx.x >> 6);
    if (n >= N) return;
    int lane = threadIdx.x & 63;
    int sub = lane >> 4, h = lane & 15;
    int start = rowStart[n], end = rowStart[n + 1];
    float acc = 0.0f;
    for (int i = start + sub; i < end; i += 4) {
        int s = eSrc[i];
        float4 b = eBasis[i];
        unsigned w = eWi[i];
        const float* yr = y1 + (size_t)s * 400;
        acc += b.x * yr[(w & 255u) * 16 + h];
        acc += b.y * yr[((w >> 8) & 255u) * 16 + h];
        acc += b.z * yr[((w >> 16) & 255u) * 16 + h];
        acc += b.w * yr[(w >> 24) * 16 + h];
    }
    acc += __shfl_xor(acc, 16, 64);
    acc += __shfl_xor(acc, 32, 64);
    if (lane < 16) agg1[(size_t)n * 16 + h] = acc;
}

// ---------------- node update 1 (mean + root + bias, relu) ----------------
__global__ void k_upd1(const float* __restrict__ x, const float* __restrict__ agg1,
                       const int* __restrict__ rowStart, const float* __restrict__ root1,
                       const float* __restrict__ bias1, float* __restrict__ h1, int N) {
    int n = blockIdx.x * 256 + threadIdx.x;
    if (n >= N) return;
    float inv = 1.0f / (float)max(rowStart[n + 1] - rowStart[n], 1);
    float r[16];
#pragma unroll
    for (int h = 0; h < 16; h++) r[h] = agg1[(size_t)n * 16 + h] * inv + bias1[h];
    const float* xrow = x + (size_t)n * 64;
    for (int i = 0; i < 64; i++) {
        float xi = xrow[i];
        const float* rr = root1 + i * 16;
#pragma unroll
        for (int h = 0; h < 16; h++) r[h] += xi * rr[h];
    }
    float* ho = h1 + (size_t)n * 16;
#pragma unroll
    for (int h = 0; h < 16; h++) ho[h] = fmaxf(r[h], 0.0f);
}

// ---------------- layer-2 messages, written contiguously at sorted position ----------------
__global__ void k_msg2(const int* __restrict__ eSrc, const float4* __restrict__ eBasis,
                       const unsigned* __restrict__ eWi, const float* __restrict__ h1,
                       const float* __restrict__ W2p, float4* __restrict__ msg2, int E) {
    int e = blockIdx.x * 256 + threadIdx.x;
    if (e >= E) return;
    int s = eSrc[e];
    float4 b = eBasis[e];
    unsigned w = eWi[e];
    float bt[4] = {b.x, b.y, b.z, b.w};
    int kk[4] = {(int)(w & 255u), (int)((w >> 8) & 255u),
                 (int)((w >> 16) & 255u), (int)(w >> 24)};
    float hreg[16];
    const float4* hp = (const float4*)(h1 + (size_t)s * 16);
#pragma unroll
    for (int j = 0; j < 4; j++) {
        float4 v = hp[j];
        hreg[4 * j + 0] = v.x; hreg[4 * j + 1] = v.y;
        hreg[4 * j + 2] = v.z; hreg[4 * j + 3] = v.w;
    }
    float a0 = 0, a1 = 0, a2 = 0, a3 = 0, a4 = 0, a5 = 0, a6 = 0;
#pragma unroll
    for (int t = 0; t < 4; t++) {
        const float4* p = (const float4*)(W2p + kk[t] * 128);
        float bb = bt[t];
#pragma unroll
        for (int i = 0; i < 16; i++) {
            float wv = bb * hreg[i];
            float4 lo = p[2 * i], hi = p[2 * i + 1];
            a0 += wv * lo.x; a1 += wv * lo.y; a2 += wv * lo.z; a3 += wv * lo.w;
            a4 += wv * hi.x; a5 += wv * hi.y; a6 += wv * hi.z;
        }
    }
    msg2[2 * e]     = make_float4(a0, a1, a2, a3);
    msg2[2 * e + 1] = make_float4(a4, a5, a6, 0.0f);
}

// ---------------- final: segment-sum msg2 + root + bias + log_softmax ----------------
__global__ void k_fin2(const float* __restrict__ h1, const float4* __restrict__ msg2,
                       const int* __restrict__ rowStart, const float* __restrict__ root2,
                       const float* __restrict__ bias2, float* __restrict__ out, int N) {
    int n = blockIdx.x * 256 + threadIdx.x;
    if (n >= N) return;
    int start = rowStart[n], end = rowStart[n + 1];
    float z[7] = {0, 0, 0, 0, 0, 0, 0};
    for (int i = start; i < end; i++) {
        float4 a = msg2[2 * i], bq = msg2[2 * i + 1];
        z[0] += a.x; z[1] += a.y; z[2] += a.z; z[3] += a.w;
        z[4] += bq.x; z[5] += bq.y; z[6] += bq.z;
    }
    float inv = 1.0f / (float)max(end - start, 1);
#pragma unroll
    for (int c = 0; c < 7; c++) z[c] = z[c] * inv + bias2[c];
    const float* hrow = h1 + (size_t)n * 16;
#pragma unroll
    for (int i = 0; i < 16; i++) {
        float hi = hrow[i];
        const float* rr = root2 + i * 7;
#pragma unroll
        for (int c = 0; c < 7; c++) z[c] += hi * rr[c];
    }
    float m = z[0];
#pragma unroll
    for (int c = 1; c < 7; c++) m = fmaxf(m, z[c]);
    float ssum = 0.0f;
#pragma unroll
    for (int c = 0; c < 7; c++) ssum += expf(z[c] - m);
    float ls = logf(ssum);
    float* orow = out + (size_t)n * 7;
#pragma unroll
    for (int c = 0; c < 7; c++) orow[c] = z[c] - m - ls;
}

extern "C" void kernel_launch(void* const* d_in, const int* in_sizes, int n_in,
                              void* d_out, int out_size, void* d_ws, size_t ws_size,
                              hipStream_t stream) {
    const float* x     = (const float*)d_in[0];
    const int*   ei    = (const int*)d_in[1];
    const float* attr  = (const float*)d_in[2];
    const float* W1    = (const float*)d_in[3];
    const float* root1 = (const float*)d_in[4];
    const float* bias1 = (const float*)d_in[5];
    const float* W2    = (const float*)d_in[6];
    const float* root2 = (const float*)d_in[7];
    const float* bias2 = (const float*)d_in[8];
    float* out = (float*)d_out;

    int N = in_sizes[0] / FIN;
    int E = in_sizes[1] / 2;

    char* w = (char*)d_ws;
    size_t off = 0;
    auto alloc = [&](size_t bytes) -> void* {
        void* p = w + off;
        off += (bytes + 255) & ~(size_t)255;
        return p;
    };
    int*      cnt      = (int*)alloc((size_t)N * 4);
    int*      rowStart = (int*)alloc((size_t)(N + 1) * 4);
    int*      cursor   = (int*)alloc((size_t)N * 4);
    int*      eSrc     = (int*)alloc((size_t)E * 4);
    float4*   eBasis   = (float4*)alloc((size_t)E * 16);
    unsigned* eWi      = (unsigned*)alloc((size_t)E * 4);
    float*    agg1     = (float*)alloc((size_t)N * 64);
    float*    h1       = (float*)alloc((size_t)N * 64);
    float*    B1t      = (float*)alloc((size_t)KK2 * FIN * HH * 4);
    float*    W2p      = (float*)alloc((size_t)KK2 * HH * 8 * 4);
    float*    y1       = (float*)alloc((size_t)N * 400 * 4);
    float4*   msg2     = (float4*)y1;   // alias: y1 dead after k_agg1
    (void)ws_size; (void)n_in; (void)out_size;

    hipMemsetAsync(cnt, 0, (size_t)N * 4, stream);

    int ebl = (E + 255) / 256;
    int nbl = (N + 255) / 256;

    k_hist<<<ebl, 256, 0, stream>>>(ei, cnt, E);
    k_scan<<<1, 1024, 0, stream>>>(cnt, rowStart, cursor, N);
    k_scatter<<<ebl, 256, 0, stream>>>(attr, ei, cursor, eSrc, eBasis, eWi, E);
    k_prepW<<<(KK2 * FIN * HH + 255) / 256, 256, 0, stream>>>(W1, W2, B1t, W2p);
    k_y1<<<4 * nbl, 256, 0, stream>>>(x, B1t, y1, N, nbl);
    k_agg1<<<(N + 3) / 4, 256, 0, stream>>>(rowStart, eSrc, eBasis, eWi, y1, agg1, N);
    k_upd1<<<nbl, 256, 0, stream>>>(x, agg1, rowStart, root1, bias1, h1, N);
    k_msg2<<<ebl, 256, 0, stream>>>(eSrc, eBasis, eWi, h1, W2p, msg2, E);
    k_fin2<<<nbl, 256, 0, stream>>>(h1, msg2, rowStart, root2, bias2, out, N);
}

// Round 3
// 420.916 us; speedup vs baseline: 2.9609x; 1.4210x over previous
//
#include <hip/hip_runtime.h>

#define KK2 25
#define FIN 64
#define HH 16
#define CC 7

// ---------------- histogram of dst degrees (int atomics) ----------------
__global__ void k_hist(const int* __restrict__ ei, int* __restrict__ cnt, int E) {
    int e = blockIdx.x * 256 + threadIdx.x;
    if (e < E) atomicAdd(&cnt[ei[E + e]], 1);
}

// ---------------- single-block exclusive scan over N counts ----------------
__global__ __launch_bounds__(1024) void k_scan(const int* __restrict__ cnt,
                                               int* __restrict__ rowStart,
                                               int* __restrict__ cursor, int N) {
    int t = threadIdx.x;
    const int CH = (N + 1023) / 1024;
    int base = t * CH, end = min(base + CH, N);
    int local = 0;
    for (int i = base; i < end; i++) local += cnt[i];
    __shared__ int sd[1024];
    sd[t] = local;
    __syncthreads();
    for (int off = 1; off < 1024; off <<= 1) {
        int v = (t >= off) ? sd[t - off] : 0;
        __syncthreads();
        sd[t] += v;
        __syncthreads();
    }
    int run = (t == 0) ? 0 : sd[t - 1];
    for (int i = base; i < end; i++) {
        rowStart[i] = run; cursor[i] = run; run += cnt[i];
    }
    if (base < N && end == N) rowStart[N] = run;
}

// ---------------- scatter edges into dst-sorted order (basis computed inline) ----------------
__global__ void k_scatter(const float* __restrict__ attr, const int* __restrict__ ei,
                          int* __restrict__ cursor, int* __restrict__ eSrc,
                          float4* __restrict__ eBasis, unsigned* __restrict__ eWi, int E) {
    int e = blockIdx.x * 256 + threadIdx.x;
    if (e >= E) return;
    float v0 = attr[2 * e] * 4.0f, v1 = attr[2 * e + 1] * 4.0f;
    float l0 = floorf(v0), l1 = floorf(v1);
    float f0 = v0 - l0, f1 = v1 - l1;
    int i0 = (int)l0, i1 = (int)l1;
    int i0a = min(max(i0, 0), 4), i0b = min(max(i0 + 1, 0), 4);
    int i1a = min(max(i1, 0), 4), i1b = min(max(i1 + 1, 0), 4);
    float4 b;
    b.x = (1.0f - f0) * (1.0f - f1);
    b.y = f0 * (1.0f - f1);
    b.z = (1.0f - f0) * f1;
    b.w = f0 * f1;
    unsigned pack = (unsigned)(i0a * 5 + i1a) | ((unsigned)(i0b * 5 + i1a) << 8) |
                    ((unsigned)(i0a * 5 + i1b) << 16) | ((unsigned)(i0b * 5 + i1b) << 24);
    int s = ei[e], d = ei[E + e];
    int pos = atomicAdd(&cursor[d], 1);
    eSrc[pos] = s;
    eBasis[pos] = b;
    eWi[pos] = pack;
}

// ---------------- repack weights ----------------
__global__ void k_prepW(const float* __restrict__ W1, const float* __restrict__ W2,
                        float* __restrict__ B1t, float* __restrict__ W2p) {
    int tid = blockIdx.x * 256 + threadIdx.x;
    if (tid < KK2 * FIN * HH) {
        int c = tid >> 6, i = tid & 63;
        int k = c >> 4, h = c & 15;
        B1t[tid] = W1[(k * FIN + i) * HH + h];
    }
    if (tid < KK2 * HH * CC) {
        int k = tid / (HH * CC), r = tid % (HH * CC);
        int i = r / CC, c = r % CC;
        W2p[(k * HH + i) * 8 + c] = W2[tid];
    }
}

// ---------------- y1 = x @ W1 (all 25 kernels), [N,400], float4 stores ----------------
__global__ void k_y1(const float* __restrict__ x, const float* __restrict__ B1t,
                     float* __restrict__ y1, int N, int nb) {
    int q = blockIdx.x / nb;                  // 0..3, block-uniform
    int n = (blockIdx.x % nb) * 256 + threadIdx.x;
    if (n >= N) return;
    float4 xr[16];
    const float4* xp = (const float4*)(x + (size_t)n * 64);
#pragma unroll
    for (int i = 0; i < 16; i++) xr[i] = xp[i];
    const float* B = B1t + q * 100 * 64;
    float4* yo = (float4*)(y1 + (size_t)n * 400 + q * 100);
    for (int cg = 0; cg < 25; cg++) {
        float a0 = 0, a1 = 0, a2 = 0, a3 = 0;
        const float4* b0 = (const float4*)(B + (cg * 4 + 0) * 64);
        const float4* b1 = (const float4*)(B + (cg * 4 + 1) * 64);
        const float4* b2 = (const float4*)(B + (cg * 4 + 2) * 64);
        const float4* b3 = (const float4*)(B + (cg * 4 + 3) * 64);
#pragma unroll
        for (int i = 0; i < 16; i++) {
            float4 xi = xr[i];
            float4 v0 = b0[i], v1 = b1[i], v2 = b2[i], v3 = b3[i];
            a0 += xi.x * v0.x + xi.y * v0.y + xi.z * v0.z + xi.w * v0.w;
            a1 += xi.x * v1.x + xi.y * v1.y + xi.z * v1.z + xi.w * v1.w;
            a2 += xi.x * v2.x + xi.y * v2.y + xi.z * v2.z + xi.w * v2.w;
            a3 += xi.x * v3.x + xi.y * v3.y + xi.z * v3.z + xi.w * v3.w;
        }
        yo[cg] = make_float4(a0, a1, a2, a3);
    }
}

// ---------------- layer-1 aggregation: one wave per node, no atomics ----------------
__global__ void k_agg1(const int* __restrict__ rowStart, const int* __restrict__ eSrc,
                       const float4* __restrict__ eBasis, const unsigned* __restrict__ eWi,
                       const float* __restrict__ y1, float* __restrict__ agg1, int N) {
    int n = blockIdx.x * 4 + (threadIdx.x >> 6);
    if (n >= N) return;
    int lane = threadIdx.x & 63;
    int sub = lane >> 4, h = lane & 15;
    int start = rowStart[n], end = rowStart[n + 1];
    float acc = 0.0f;
    for (int i = start + sub; i < end; i += 4) {
        int s = eSrc[i];
        float4 b = eBasis[i];
        unsigned w = eWi[i];
        const float* yr = y1 + (size_t)s * 400;
        acc += b.x * yr[(w & 255u) * 16 + h];
        acc += b.y * yr[((w >> 8) & 255u) * 16 + h];
        acc += b.z * yr[((w >> 16) & 255u) * 16 + h];
        acc += b.w * yr[(w >> 24) * 16 + h];
    }
    acc += __shfl_xor(acc, 16, 64);
    acc += __shfl_xor(acc, 32, 64);
    if (lane < 16) agg1[(size_t)n * 16 + h] = acc;
}

// ---------------- node update 1 (mean + root + bias, relu) ----------------
__global__ void k_upd1(const float* __restrict__ x, const float* __restrict__ agg1,
                       const int* __restrict__ rowStart, const float* __restrict__ root1,
                       const float* __restrict__ bias1, float* __restrict__ h1, int N) {
    int n = blockIdx.x * 256 + threadIdx.x;
    if (n >= N) return;
    float inv = 1.0f / (float)max(rowStart[n + 1] - rowStart[n], 1);
    float r[16];
#pragma unroll
    for (int h = 0; h < 16; h++) r[h] = agg1[(size_t)n * 16 + h] * inv + bias1[h];
    const float* xrow = x + (size_t)n * 64;
    for (int i = 0; i < 64; i++) {
        float xi = xrow[i];
        const float* rr = root1 + i * 16;
#pragma unroll
        for (int h = 0; h < 16; h++) r[h] += xi * rr[h];
    }
    float* ho = h1 + (size_t)n * 16;
#pragma unroll
    for (int h = 0; h < 16; h++) ho[h] = fmaxf(r[h], 0.0f);
}

// ---------------- y2 = h1 @ W2 (all 25 kernels), [N, 25*8] padded ----------------
__global__ void k_y2(const float* __restrict__ h1, const float* __restrict__ W2p,
                     float* __restrict__ y2, int N) {
    int n = blockIdx.x * 256 + threadIdx.x;
    if (n >= N) return;
    float h[16];
    const float4* hp = (const float4*)(h1 + (size_t)n * 16);
#pragma unroll
    for (int j = 0; j < 4; j++) {
        float4 v = hp[j];
        h[4 * j] = v.x; h[4 * j + 1] = v.y; h[4 * j + 2] = v.z; h[4 * j + 3] = v.w;
    }
    float4* yo = (float4*)(y2 + (size_t)n * 200);
    for (int k = 0; k < 25; k++) {
        float4 zlo = make_float4(0, 0, 0, 0), zhi = make_float4(0, 0, 0, 0);
        const float4* wp = (const float4*)(W2p + k * 128);
#pragma unroll
        for (int i = 0; i < 16; i++) {
            float hi = h[i];
            float4 lo = wp[2 * i], hv = wp[2 * i + 1];
            zlo.x += hi * lo.x; zlo.y += hi * lo.y; zlo.z += hi * lo.z; zlo.w += hi * lo.w;
            zhi.x += hi * hv.x; zhi.y += hi * hv.y; zhi.z += hi * hv.z; zhi.w += hi * hv.w;
        }
        yo[2 * k] = zlo;
        yo[2 * k + 1] = zhi;
    }
}

// ---------------- layer-2 aggregation: one wave per node, gathers from y2 ----------------
__global__ void k_agg2(const int* __restrict__ rowStart, const int* __restrict__ eSrc,
                       const float4* __restrict__ eBasis, const unsigned* __restrict__ eWi,
                       const float* __restrict__ y2, float* __restrict__ agg2, int N) {
    int n = blockIdx.x * 4 + (threadIdx.x >> 6);
    if (n >= N) return;
    int lane = threadIdx.x & 63;
    int sub = lane >> 3, c = lane & 7;        // 8 edge-subgroups x 8 channels
    int start = rowStart[n], end = rowStart[n + 1];
    float acc = 0.0f;
    for (int i = start + sub; i < end; i += 8) {
        int s = eSrc[i];
        float4 b = eBasis[i];
        unsigned w = eWi[i];
        const float* yr = y2 + (size_t)s * 200;
        acc += b.x * yr[(w & 255u) * 8 + c];
        acc += b.y * yr[((w >> 8) & 255u) * 8 + c];
        acc += b.z * yr[((w >> 16) & 255u) * 8 + c];
        acc += b.w * yr[(w >> 24) * 8 + c];
    }
    acc += __shfl_xor(acc, 8, 64);
    acc += __shfl_xor(acc, 16, 64);
    acc += __shfl_xor(acc, 32, 64);
    if (lane < 8) agg2[(size_t)n * 8 + c] = acc;
}

// ---------------- final: mean + root + bias + log_softmax ----------------
__global__ void k_fin2(const float* __restrict__ h1, const float* __restrict__ agg2,
                       const int* __restrict__ rowStart, const float* __restrict__ root2,
                       const float* __restrict__ bias2, float* __restrict__ out, int N) {
    int n = blockIdx.x * 256 + threadIdx.x;
    if (n >= N) return;
    float inv = 1.0f / (float)max(rowStart[n + 1] - rowStart[n], 1);
    float z[7];
#pragma unroll
    for (int c = 0; c < 7; c++) z[c] = agg2[(size_t)n * 8 + c] * inv + bias2[c];
    const float* hrow = h1 + (size_t)n * 16;
#pragma unroll
    for (int i = 0; i < 16; i++) {
        float hi = hrow[i];
        const float* rr = root2 + i * 7;
#pragma unroll
        for (int c = 0; c < 7; c++) z[c] += hi * rr[c];
    }
    float m = z[0];
#pragma unroll
    for (int c = 1; c < 7; c++) m = fmaxf(m, z[c]);
    float ssum = 0.0f;
#pragma unroll
    for (int c = 0; c < 7; c++) ssum += expf(z[c] - m);
    float ls = logf(ssum);
    float* orow = out + (size_t)n * 7;
#pragma unroll
    for (int c = 0; c < 7; c++) orow[c] = z[c] - m - ls;
}

extern "C" void kernel_launch(void* const* d_in, const int* in_sizes, int n_in,
                              void* d_out, int out_size, void* d_ws, size_t ws_size,
                              hipStream_t stream) {
    const float* x     = (const float*)d_in[0];
    const int*   ei    = (const int*)d_in[1];
    const float* attr  = (const float*)d_in[2];
    const float* W1    = (const float*)d_in[3];
    const float* root1 = (const float*)d_in[4];
    const float* bias1 = (const float*)d_in[5];
    const float* W2    = (const float*)d_in[6];
    const float* root2 = (const float*)d_in[7];
    const float* bias2 = (const float*)d_in[8];
    float* out = (float*)d_out;

    int N = in_sizes[0] / FIN;
    int E = in_sizes[1] / 2;

    char* w = (char*)d_ws;
    size_t off = 0;
    auto alloc = [&](size_t bytes) -> void* {
        void* p = w + off;
        off += (bytes + 255) & ~(size_t)255;
        return p;
    };
    int*      cnt      = (int*)alloc((size_t)N * 4);
    int*      rowStart = (int*)alloc((size_t)(N + 1) * 4);
    int*      cursor   = (int*)alloc((size_t)N * 4);
    int*      eSrc     = (int*)alloc((size_t)E * 4);
    float4*   eBasis   = (float4*)alloc((size_t)E * 16);
    unsigned* eWi      = (unsigned*)alloc((size_t)E * 4);
    float*    agg1     = (float*)alloc((size_t)N * 64);
    float*    h1       = (float*)alloc((size_t)N * 64);
    float*    agg2     = (float*)alloc((size_t)N * 32);
    float*    B1t      = (float*)alloc((size_t)KK2 * FIN * HH * 4);
    float*    W2p      = (float*)alloc((size_t)KK2 * HH * 8 * 4);
    float*    y1       = (float*)alloc((size_t)N * 400 * 4);
    float*    y2       = y1;   // alias: y1 dead after k_agg1; y2 is [N,200]
    (void)ws_size; (void)n_in; (void)out_size;

    hipMemsetAsync(cnt, 0, (size_t)N * 4, stream);

    int ebl = (E + 255) / 256;
    int nbl = (N + 255) / 256;

    k_hist<<<ebl, 256, 0, stream>>>(ei, cnt, E);
    k_scan<<<1, 1024, 0, stream>>>(cnt, rowStart, cursor, N);
    k_scatter<<<ebl, 256, 0, stream>>>(attr, ei, cursor, eSrc, eBasis, eWi, E);
    k_prepW<<<(KK2 * FIN * HH + 255) / 256, 256, 0, stream>>>(W1, W2, B1t, W2p);
    k_y1<<<4 * nbl, 256, 0, stream>>>(x, B1t, y1, N, nbl);
    k_agg1<<<(N + 3) / 4, 256, 0, stream>>>(rowStart, eSrc, eBasis, eWi, y1, agg1, N);
    k_upd1<<<nbl, 256, 0, stream>>>(x, agg1, rowStart, root1, bias1, h1, N);
    k_y2<<<nbl, 256, 0, stream>>>(h1, W2p, y2, N);
    k_agg2<<<(N + 3) / 4, 256, 0, stream>>>(rowStart, eSrc, eBasis, eWi, y2, agg2, N);
    k_fin2<<<nbl, 256, 0, stream>>>(h1, agg2, rowStart, root2, bias2, out, N);
}

// Round 4
// 323.677 us; speedup vs baseline: 3.8505x; 1.3004x over previous
//
#include <hip/hip_runtime.h>

#define KK2 25
#define FIN 64
#define HH 16
#define CC 7

#define SCAN_VPT 4
#define SCAN_BLK 256
#define SCAN_CHUNK (SCAN_VPT * SCAN_BLK)   // 1024 elements per block

// ---------------- histogram of dst degrees (int atomics) ----------------
__global__ void k_hist(const int* __restrict__ ei, int* __restrict__ cnt, int E) {
    int e = blockIdx.x * 256 + threadIdx.x;
    if (e < E) atomicAdd(&cnt[ei[E + e]], 1);
}

// ---------------- scan pass 1: per-block sums ----------------
__global__ void k_bsum(const int* __restrict__ cnt, int* __restrict__ bsum, int N) {
    int b = blockIdx.x, t = threadIdx.x;
    int base = b * SCAN_CHUNK + t * SCAN_VPT;
    int s = 0;
#pragma unroll
    for (int j = 0; j < SCAN_VPT; j++) {
        int i = base + j;
        if (i < N) s += cnt[i];
    }
#pragma unroll
    for (int d = 1; d < 64; d <<= 1) s += __shfl_xor(s, d, 64);
    __shared__ int sd[SCAN_BLK / 64];
    if ((t & 63) == 0) sd[t >> 6] = s;
    __syncthreads();
    if (t == 0) {
        int tot = 0;
        for (int w = 0; w < SCAN_BLK / 64; w++) tot += sd[w];
        bsum[b] = tot;
    }
}

// ---------------- scan pass 2: scan the block sums (single small block) ----------------
__global__ void k_bscan(const int* __restrict__ bsum, int* __restrict__ boff, int nblk) {
    int t = threadIdx.x;            // 256 threads, nblk <= 256
    __shared__ int sd[256];
    int v = (t < nblk) ? bsum[t] : 0;
    sd[t] = v;
    __syncthreads();
    for (int off = 1; off < 256; off <<= 1) {
        int u = (t >= off) ? sd[t - off] : 0;
        __syncthreads();
        sd[t] += u;
        __syncthreads();
    }
    boff[t] = sd[t] - v;            // exclusive prefix
}

// ---------------- scan pass 3: local scan + block offset -> rowStart, cursor ----------------
__global__ void k_sfin(const int* __restrict__ cnt, const int* __restrict__ boff,
                       int* __restrict__ rowStart, int* __restrict__ cursor, int N) {
    int b = blockIdx.x, t = threadIdx.x;
    int base = b * SCAN_CHUNK + t * SCAN_VPT;
    int v[SCAN_VPT];
    int s = 0;
#pragma unroll
    for (int j = 0; j < SCAN_VPT; j++) {
        int i = base + j;
        v[j] = (i < N) ? cnt[i] : 0;
        s += v[j];
    }
    __shared__ int sd[SCAN_BLK];
    sd[t] = s;
    __syncthreads();
    for (int off = 1; off < SCAN_BLK; off <<= 1) {
        int u = (t >= off) ? sd[t - off] : 0;
        __syncthreads();
        sd[t] += u;
        __syncthreads();
    }
    int run = sd[t] - s + boff[b];
#pragma unroll
    for (int j = 0; j < SCAN_VPT; j++) {
        int i = base + j;
        if (i < N) {
            rowStart[i] = run;
            cursor[i] = run;
            run += v[j];
            if (i == N - 1) rowStart[N] = run;
        }
    }
}

// ---------------- scatter edges into dst-sorted order (basis computed inline) ----------------
__global__ void k_scatter(const float* __restrict__ attr, const int* __restrict__ ei,
                          int* __restrict__ cursor, int* __restrict__ eSrc,
                          float4* __restrict__ eBasis, unsigned* __restrict__ eWi, int E) {
    int e = blockIdx.x * 256 + threadIdx.x;
    if (e >= E) return;
    float v0 = attr[2 * e] * 4.0f, v1 = attr[2 * e + 1] * 4.0f;
    float l0 = floorf(v0), l1 = floorf(v1);
    float f0 = v0 - l0, f1 = v1 - l1;
    int i0 = (int)l0, i1 = (int)l1;
    int i0a = min(max(i0, 0), 4), i0b = min(max(i0 + 1, 0), 4);
    int i1a = min(max(i1, 0), 4), i1b = min(max(i1 + 1, 0), 4);
    float4 b;
    b.x = (1.0f - f0) * (1.0f - f1);
    b.y = f0 * (1.0f - f1);
    b.z = (1.0f - f0) * f1;
    b.w = f0 * f1;
    unsigned pack = (unsigned)(i0a * 5 + i1a) | ((unsigned)(i0b * 5 + i1a) << 8) |
                    ((unsigned)(i0a * 5 + i1b) << 16) | ((unsigned)(i0b * 5 + i1b) << 24);
    int s = ei[e], d = ei[E + e];
    int pos = atomicAdd(&cursor[d], 1);
    eSrc[pos] = s;
    eBasis[pos] = b;
    eWi[pos] = pack;
}

// ---------------- repack weights ----------------
__global__ void k_prepW(const float* __restrict__ W1, const float* __restrict__ W2,
                        float* __restrict__ B1t, float* __restrict__ W2p) {
    int tid = blockIdx.x * 256 + threadIdx.x;
    if (tid < KK2 * FIN * HH) {
        int c = tid >> 6, i = tid & 63;
        int k = c >> 4, h = c & 15;
        B1t[tid] = W1[(k * FIN + i) * HH + h];
    }
    if (tid < KK2 * HH * CC) {
        int k = tid / (HH * CC), r = tid % (HH * CC);
        int i = r / CC, c = r % CC;
        W2p[(k * HH + i) * 8 + c] = W2[tid];
    }
}

// ---------------- y1 = x @ W1 (all 25 kernels), [N,400], float4 stores ----------------
__global__ void k_y1(const float* __restrict__ x, const float* __restrict__ B1t,
                     float* __restrict__ y1, int N, int nb) {
    int q = blockIdx.x / nb;                  // 0..3, block-uniform
    int n = (blockIdx.x % nb) * 256 + threadIdx.x;
    if (n >= N) return;
    float4 xr[16];
    const float4* xp = (const float4*)(x + (size_t)n * 64);
#pragma unroll
    for (int i = 0; i < 16; i++) xr[i] = xp[i];
    const float* B = B1t + q * 100 * 64;
    float4* yo = (float4*)(y1 + (size_t)n * 400 + q * 100);
    for (int cg = 0; cg < 25; cg++) {
        float a0 = 0, a1 = 0, a2 = 0, a3 = 0;
        const float4* b0 = (const float4*)(B + (cg * 4 + 0) * 64);
        const float4* b1 = (const float4*)(B + (cg * 4 + 1) * 64);
        const float4* b2 = (const float4*)(B + (cg * 4 + 2) * 64);
        const float4* b3 = (const float4*)(B + (cg * 4 + 3) * 64);
#pragma unroll
        for (int i = 0; i < 16; i++) {
            float4 xi = xr[i];
            float4 v0 = b0[i], v1 = b1[i], v2 = b2[i], v3 = b3[i];
            a0 += xi.x * v0.x + xi.y * v0.y + xi.z * v0.z + xi.w * v0.w;
            a1 += xi.x * v1.x + xi.y * v1.y + xi.z * v1.z + xi.w * v1.w;
            a2 += xi.x * v2.x + xi.y * v2.y + xi.z * v2.z + xi.w * v2.w;
            a3 += xi.x * v3.x + xi.y * v3.y + xi.z * v3.z + xi.w * v3.w;
        }
        yo[cg] = make_float4(a0, a1, a2, a3);
    }
}

// ---------------- layer-1 aggregation: one wave per node, no atomics ----------------
__global__ void k_agg1(const int* __restrict__ rowStart, const int* __restrict__ eSrc,
                       const float4* __restrict__ eBasis, const unsigned* __restrict__ eWi,
                       const float* __restrict__ y1, float* __restrict__ agg1, int N) {
    int n = blockIdx.x * 4 + (threadIdx.x >> 6);
    if (n >= N) return;
    int lane = threadIdx.x & 63;
    int sub = lane >> 4, h = lane & 15;
    int start = rowStart[n], end = rowStart[n + 1];
    float acc = 0.0f;
    for (int i = start + sub; i < end; i += 4) {
        int s = eSrc[i];
        float4 b = eBasis[i];
        unsigned w = eWi[i];
        const float* yr = y1 + (size_t)s * 400;
        acc += b.x * yr[(w & 255u) * 16 + h];
        acc += b.y * yr[((w >> 8) & 255u) * 16 + h];
        acc += b.z * yr[((w >> 16) & 255u) * 16 + h];
        acc += b.w * yr[(w >> 24) * 16 + h];
    }
    acc += __shfl_xor(acc, 16, 64);
    acc += __shfl_xor(acc, 32, 64);
    if (lane < 16) agg1[(size_t)n * 16 + h] = acc;
}

// ---------------- node update 1 (mean + root + bias, relu) ----------------
__global__ void k_upd1(const float* __restrict__ x, const float* __restrict__ agg1,
                       const int* __restrict__ rowStart, const float* __restrict__ root1,
                       const float* __restrict__ bias1, float* __restrict__ h1, int N) {
    int n = blockIdx.x * 256 + threadIdx.x;
    if (n >= N) return;
    float inv = 1.0f / (float)max(rowStart[n + 1] - rowStart[n], 1);
    float r[16];
#pragma unroll
    for (int h = 0; h < 16; h++) r[h] = agg1[(size_t)n * 16 + h] * inv + bias1[h];
    const float* xrow = x + (size_t)n * 64;
    for (int i = 0; i < 64; i++) {
        float xi = xrow[i];
        const float* rr = root1 + i * 16;
#pragma unroll
        for (int h = 0; h < 16; h++) r[h] += xi * rr[h];
    }
    float* ho = h1 + (size_t)n * 16;
#pragma unroll
    for (int h = 0; h < 16; h++) ho[h] = fmaxf(r[h], 0.0f);
}

// ---------------- y2 = h1 @ W2 (all 25 kernels), [N, 25*8] padded ----------------
__global__ void k_y2(const float* __restrict__ h1, const float* __restrict__ W2p,
                     float* __restrict__ y2, int N) {
    int n = blockIdx.x * 256 + threadIdx.x;
    if (n >= N) return;
    float h[16];
    const float4* hp = (const float4*)(h1 + (size_t)n * 16);
#pragma unroll
    for (int j = 0; j < 4; j++) {
        float4 v = hp[j];
        h[4 * j] = v.x; h[4 * j + 1] = v.y; h[4 * j + 2] = v.z; h[4 * j + 3] = v.w;
    }
    float4* yo = (float4*)(y2 + (size_t)n * 200);
    for (int k = 0; k < 25; k++) {
        float4 zlo = make_float4(0, 0, 0, 0), zhi = make_float4(0, 0, 0, 0);
        const float4* wp = (const float4*)(W2p + k * 128);
#pragma unroll
        for (int i = 0; i < 16; i++) {
            float hi = h[i];
            float4 lo = wp[2 * i], hv = wp[2 * i + 1];
            zlo.x += hi * lo.x; zlo.y += hi * lo.y; zlo.z += hi * lo.z; zlo.w += hi * lo.w;
            zhi.x += hi * hv.x; zhi.y += hi * hv.y; zhi.z += hi * hv.z; zhi.w += hi * hv.w;
        }
        yo[2 * k] = zlo;
        yo[2 * k + 1] = zhi;
    }
}

// ---------------- layer-2 aggregation: one wave per node, gathers from y2 ----------------
__global__ void k_agg2(const int* __restrict__ rowStart, const int* __restrict__ eSrc,
                       const float4* __restrict__ eBasis, const unsigned* __restrict__ eWi,
                       const float* __restrict__ y2, float* __restrict__ agg2, int N) {
    int n = blockIdx.x * 4 + (threadIdx.x >> 6);
    if (n >= N) return;
    int lane = threadIdx.x & 63;
    int sub = lane >> 3, c = lane & 7;        // 8 edge-subgroups x 8 channels
    int start = rowStart[n], end = rowStart[n + 1];
    float acc = 0.0f;
    for (int i = start + sub; i < end; i += 8) {
        int s = eSrc[i];
        float4 b = eBasis[i];
        unsigned w = eWi[i];
        const float* yr = y2 + (size_t)s * 200;
        acc += b.x * yr[(w & 255u) * 8 + c];
        acc += b.y * yr[((w >> 8) & 255u) * 8 + c];
        acc += b.z * yr[((w >> 16) & 255u) * 8 + c];
        acc += b.w * yr[(w >> 24) * 8 + c];
    }
    acc += __shfl_xor(acc, 8, 64);
    acc += __shfl_xor(acc, 16, 64);
    acc += __shfl_xor(acc, 32, 64);
    if (lane < 8) agg2[(size_t)n * 8 + c] = acc;
}

// ---------------- final: mean + root + bias + log_softmax ----------------
__global__ void k_fin2(const float* __restrict__ h1, const float* __restrict__ agg2,
                       const int* __restrict__ rowStart, const float* __restrict__ root2,
                       const float* __restrict__ bias2, float* __restrict__ out, int N) {
    int n = blockIdx.x * 256 + threadIdx.x;
    if (n >= N) return;
    float inv = 1.0f / (float)max(rowStart[n + 1] - rowStart[n], 1);
    float z[7];
#pragma unroll
    for (int c = 0; c < 7; c++) z[c] = agg2[(size_t)n * 8 + c] * inv + bias2[c];
    const float* hrow = h1 + (size_t)n * 16;
#pragma unroll
    for (int i = 0; i < 16; i++) {
        float hi = hrow[i];
        const float* rr = root2 + i * 7;
#pragma unroll
        for (int c = 0; c < 7; c++) z[c] += hi * rr[c];
    }
    float m = z[0];
#pragma unroll
    for (int c = 1; c < 7; c++) m = fmaxf(m, z[c]);
    float ssum = 0.0f;
#pragma unroll
    for (int c = 0; c < 7; c++) ssum += expf(z[c] - m);
    float ls = logf(ssum);
    float* orow = out + (size_t)n * 7;
#pragma unroll
    for (int c = 0; c < 7; c++) orow[c] = z[c] - m - ls;
}

extern "C" void kernel_launch(void* const* d_in, const int* in_sizes, int n_in,
                              void* d_out, int out_size, void* d_ws, size_t ws_size,
                              hipStream_t stream) {
    const float* x     = (const float*)d_in[0];
    const int*   ei    = (const int*)d_in[1];
    const float* attr  = (const float*)d_in[2];
    const float* W1    = (const float*)d_in[3];
    const float* root1 = (const float*)d_in[4];
    const float* bias1 = (const float*)d_in[5];
    const float* W2    = (const float*)d_in[6];
    const float* root2 = (const float*)d_in[7];
    const float* bias2 = (const float*)d_in[8];
    float* out = (float*)d_out;

    int N = in_sizes[0] / FIN;
    int E = in_sizes[1] / 2;

    char* w = (char*)d_ws;
    size_t off = 0;
    auto alloc = [&](size_t bytes) -> void* {
        void* p = w + off;
        off += (bytes + 255) & ~(size_t)255;
        return p;
    };
    int*      cnt      = (int*)alloc((size_t)N * 4);
    int*      rowStart = (int*)alloc((size_t)(N + 1) * 4);
    int*      cursor   = (int*)alloc((size_t)N * 4);
    int*      bsum     = (int*)alloc(260 * 4);
    int*      boff     = (int*)alloc(260 * 4);
    int*      eSrc     = (int*)alloc((size_t)E * 4);
    float4*   eBasis   = (float4*)alloc((size_t)E * 16);
    unsigned* eWi      = (unsigned*)alloc((size_t)E * 4);
    float*    agg1     = (float*)alloc((size_t)N * 64);
    float*    h1       = (float*)alloc((size_t)N * 64);
    float*    agg2     = (float*)alloc((size_t)N * 32);
    float*    B1t      = (float*)alloc((size_t)KK2 * FIN * HH * 4);
    float*    W2p      = (float*)alloc((size_t)KK2 * HH * 8 * 4);
    float*    y1       = (float*)alloc((size_t)N * 400 * 4);
    float*    y2       = y1;   // alias: y1 dead after k_agg1; y2 is [N,200]
    (void)ws_size; (void)n_in; (void)out_size;

    hipMemsetAsync(cnt, 0, (size_t)N * 4, stream);

    int ebl = (E + 255) / 256;
    int nbl = (N + 255) / 256;
    int sblk = (N + SCAN_CHUNK - 1) / SCAN_CHUNK;   // 49 blocks for N=50k

    k_hist<<<ebl, 256, 0, stream>>>(ei, cnt, E);
    k_bsum<<<sblk, SCAN_BLK, 0, stream>>>(cnt, bsum, N);
    k_bscan<<<1, 256, 0, stream>>>(bsum, boff, sblk);
    k_sfin<<<sblk, SCAN_BLK, 0, stream>>>(cnt, boff, rowStart, cursor, N);
    k_scatter<<<ebl, 256, 0, stream>>>(attr, ei, cursor, eSrc, eBasis, eWi, E);
    k_prepW<<<(KK2 * FIN * HH + 255) / 256, 256, 0, stream>>>(W1, W2, B1t, W2p);
    k_y1<<<4 * nbl, 256, 0, stream>>>(x, B1t, y1, N, nbl);
    k_agg1<<<(N + 3) / 4, 256, 0, stream>>>(rowStart, eSrc, eBasis, eWi, y1, agg1, N);
    k_upd1<<<nbl, 256, 0, stream>>>(x, agg1, rowStart, root1, bias1, h1, N);
    k_y2<<<nbl, 256, 0, stream>>>(h1, W2p, y2, N);
    k_agg2<<<(N + 3) / 4, 256, 0, stream>>>(rowStart, eSrc, eBasis, eWi, y2, agg2, N);
    k_fin2<<<nbl, 256, 0, stream>>>(h1, agg2, rowStart, root2, bias2, out, N);
}